// Round 11
// baseline (1170.026 us; speedup 1.0000x reference)
//
#include <hip/hip_runtime.h>
#include <hip/hip_bf16.h>

#define NNODES 100000
#define NEDGES 1600000
#define IN_F 16
#define HID 128
#define NLAYERS 8
#define BN_EPS 1e-5f
#define BLOBSZ 532480   // ushorts per blob: 8192 + 16*32768 (hi-only since r15)
#define NCLS 32         // r19: 32-way split stats

typedef __attribute__((ext_vector_type(8))) short short8;
typedef __attribute__((ext_vector_type(8))) _Float16 f16x8;
typedef __attribute__((ext_vector_type(2))) float f2_t;
typedef __attribute__((ext_vector_type(4))) float f32x4;
typedef __attribute__((ext_vector_type(4))) unsigned int uint32x4;
typedef unsigned short ushort_t;
typedef unsigned int uint_t;

// ---- fp16 helpers (r14: whole activation chain fp16) ----
__device__ __forceinline__ float f16l(uint_t u) {
  return (float)__builtin_bit_cast(_Float16, (ushort_t)(u & 0xFFFFu));
}
__device__ __forceinline__ float f16h(uint_t u) {
  return (float)__builtin_bit_cast(_Float16, (ushort_t)(u >> 16));
}
__device__ __forceinline__ ushort_t f2h(float f) {
  return __builtin_bit_cast(ushort_t, (_Float16)f);
}
__device__ __forceinline__ uint_t pk16(float x, float y) {
  return (uint_t)f2h(x) | ((uint_t)f2h(y) << 16);
}
__device__ __forceinline__ f16x8 pack8(const float* v) {
  f16x8 r;
#pragma unroll
  for (int j = 0; j < 8; ++j) r[j] = (_Float16)v[j];
  return r;
}

// nontemporal helpers (streams with no reuse; YB/X0u stay cached for reuse)
__device__ __forceinline__ f32x4 ntl4(const float* p) {
  return __builtin_nontemporal_load((const f32x4*)p);
}
__device__ __forceinline__ short8 ntl_s8(const ushort_t* p) {
  return __builtin_nontemporal_load((const short8*)p);
}

// ===================== CSR build: 2-level bucket sort (r8 win) =====================
__global__ __launch_bounds__(256) void bhist_kernel(
    const int* __restrict__ dst, int* __restrict__ bucketCnt, int E, int nbk) {
  __shared__ int cnt[256];
  int t = threadIdx.x;
  cnt[t] = 0;
  __syncthreads();
  int base = blockIdx.x * 2048 + t * 8;
#pragma unroll
  for (int j = 0; j < 8; ++j) {
    int i = base + j;
    if (i < E) atomicAdd(&cnt[dst[i] >> 9], 1);
  }
  __syncthreads();
  if (t < nbk && cnt[t]) atomicAdd(&bucketCnt[t], cnt[t]);
}

__global__ void bscan_kernel(const int* __restrict__ bucketCnt, int* __restrict__ bucketBase,
                             int* __restrict__ bucketCur, int* __restrict__ row_ptr,
                             int N, int E, int nbk) {
  __shared__ int s[256];
  int t = threadIdx.x;
  s[t] = (t < nbk) ? bucketCnt[t] : 0;
  __syncthreads();
  for (int off = 1; off < 256; off <<= 1) {
    int v = (t >= off) ? s[t - off] : 0;
    __syncthreads();
    s[t] += v;
    __syncthreads();
  }
  int excl = (t == 0) ? 0 : s[t - 1];
  if (t < nbk) { bucketBase[t] = excl; bucketCur[t] = excl; }
  if (t == nbk) bucketBase[t] = E;
  if (t == 0) row_ptr[N] = E;
}

__global__ __launch_bounds__(256) void bscatter_kernel(
    const int* __restrict__ src, const int* __restrict__ dst,
    int* __restrict__ bucketCur, int2* __restrict__ ebuf, int E, int nbk) {
  __shared__ int cnt[256];
  __shared__ int base_l[256];
  int t = threadIdx.x;
  cnt[t] = 0;
  __syncthreads();
  int base = blockIdx.x * 2048 + t * 8;
  int bj[8], lr[8], dj[8], sj[8];
#pragma unroll
  for (int j = 0; j < 8; ++j) {
    int i = base + j;
    if (i < E) {
      dj[j] = dst[i];
      sj[j] = src[i];
      bj[j] = dj[j] >> 9;
      lr[j] = atomicAdd(&cnt[bj[j]], 1);
    } else bj[j] = -1;
  }
  __syncthreads();
  if (t < nbk) base_l[t] = cnt[t] ? atomicAdd(&bucketCur[t], cnt[t]) : 0;
  __syncthreads();
#pragma unroll
  for (int j = 0; j < 8; ++j)
    if (bj[j] >= 0) ebuf[base_l[bj[j]] + lr[j]] = make_int2(dj[j], sj[j]);
}

__global__ __launch_bounds__(256) void bcsr_kernel(
    const int2* __restrict__ ebuf, const int* __restrict__ bucketBase,
    int* __restrict__ row_ptr, int* __restrict__ colb, int N) {
  __shared__ int h[512];
  __shared__ int cur[512];
  __shared__ int s2[256];
  int b = blockIdx.x, t = threadIdx.x;
  int beg = bucketBase[b], end = bucketBase[b + 1];
  h[t] = 0; h[t + 256] = 0;
  __syncthreads();
  for (int p = beg + t; p < end; p += 256) atomicAdd(&h[ebuf[p].x & 511], 1);
  __syncthreads();
  s2[t] = h[2 * t] + h[2 * t + 1];
  __syncthreads();
  for (int off = 1; off < 256; off <<= 1) {
    int v = (t >= off) ? s2[t - off] : 0;
    __syncthreads();
    s2[t] += v;
    __syncthreads();
  }
  int ep = (t == 0) ? 0 : s2[t - 1];
  cur[2 * t] = ep;
  cur[2 * t + 1] = ep + h[2 * t];
  int dg = (b << 9) + 2 * t;
  if (dg < N) row_ptr[dg] = beg + cur[2 * t];
  if (dg + 1 < N) row_ptr[dg + 1] = beg + cur[2 * t + 1];
  __syncthreads();
  for (int p = beg + t; p < end; p += 256) {
    int2 e2 = ebuf[p];
    int pos = beg + atomicAdd(&cur[e2.x & 511], 1);
    colb[pos] = e2.y;
  }
}

// =================== weight pre-convert: fp16 MFMA-frag blob (hi only, r15) ===================
__global__ void preconv_kernel(const float* __restrict__ W1_0, const float* __restrict__ W1,
                               const float* __restrict__ W2, const float* __restrict__ Wr1,
                               ushort_t* __restrict__ WB) {
  int g = blockIdx.y;
  int e = blockIdx.x * 256 + threadIdx.x;
  int KP = (g == 0) ? 32 : 128;
  if (e >= KP * 128) return;
  int k = e >> 7, n = e & 127;
  float v;
  if (g == 0) v = (k < 16) ? W1_0[k * 128 + n] : 0.0f;
  else if (g <= 7) v = W1[(size_t)(g - 1) * 16384 + e];
  else if (g <= 15) v = W2[(size_t)(g - 8) * 16384 + e];
  else v = Wr1[e];
  size_t base = (g == 0) ? 0 : (8192 + (size_t)(g - 1) * 32768);
  int unit = ((k >> 5) << 9) + ((n >> 4) << 6) + (n & 15) + (((k >> 3) & 3) << 4);
  WB[base + (size_t)unit * 8 + (k & 7)] = __builtin_bit_cast(ushort_t, (_Float16)v);
}

// ============================ layer-0 aggregation (F=16, fp32) ============================
__global__ __launch_bounds__(256) void agg16_kernel(
    const float* __restrict__ X, const int* __restrict__ rp, const int* __restrict__ colb,
    const float* __restrict__ eps, float* __restrict__ Z, int N) {
  int g = threadIdx.x >> 3;
  int l = threadIdx.x & 7;
  int n = blockIdx.x * 32 + g;
  if (n >= N) return;
  float e = 1.0f + eps[0];
  const float2* X2 = (const float2*)X;
  float2 self = X2[(size_t)n * 8 + l];
  float2 acc = make_float2(self.x * e, self.y * e);
  float2 acc2 = make_float2(0.0f, 0.0f);
  int beg = rp[n], end = rp[n + 1];
  int p = beg;
  for (; p + 4 <= end; p += 4) {
    int s0 = colb[p], s1 = colb[p + 1], s2 = colb[p + 2], s3 = colb[p + 3];
    float2 v0 = X2[(size_t)s0 * 8 + l];
    float2 v1 = X2[(size_t)s1 * 8 + l];
    float2 v2 = X2[(size_t)s2 * 8 + l];
    float2 v3 = X2[(size_t)s3 * 8 + l];
    acc.x += v0.x; acc.y += v0.y;
    acc2.x += v1.x; acc2.y += v1.y;
    acc.x += v2.x; acc.y += v2.y;
    acc2.x += v3.x; acc2.y += v3.y;
  }
  for (; p < end; ++p) {
    int s = colb[p];
    float2 v = X2[(size_t)s * 8 + l];
    acc.x += v.x; acc.y += v.y;
  }
  acc.x += acc2.x; acc.y += acc2.y;
  ((float2*)Z)[(size_t)n * 8 + l] = acc;
}

// layers 1..7 aggregation — r24: EXACT r21 scalar quad-gather (measured 73.0 us).
// r23's packed-f2 form was +1.8 us slower (insert/extract overhead, VALUBusy 56->62%).
// smode: 0 = no skip, 1 = SKIP store (first touch at L=2), 2 = SKIP += (L=4,6).
__global__ __launch_bounds__(256) void agg128_kernel(
    const ushort_t* __restrict__ Y, const float* __restrict__ av, const float* __restrict__ cv,
    const int* __restrict__ rp, const int* __restrict__ colb,
    const float* __restrict__ eps, int layer, uint_t* __restrict__ Z,
    ushort_t* __restrict__ SKIP, int smode, int N) {
  int wv = threadIdx.x >> 6;
  int lane = threadIdx.x & 63;
  int quad = lane >> 4;    // 0..3: which edge of a 4-group this lane serves
  int l16 = lane & 15;     // position within the 256 B row
  int n = blockIdx.x * 4 + wv;
  if (n >= N) return;
  float e = 1.0f + eps[layer];
  // 8 channels per lane: cols l16*8 .. l16*8+7
  float4 aA = *(const float4*)(av + l16 * 8);
  float4 aB = *(const float4*)(av + l16 * 8 + 4);
  float4 cA = *(const float4*)(cv + l16 * 8);
  float4 cB = *(const float4*)(cv + l16 * 8 + 4);
  float a8[8] = {aA.x, aA.y, aA.z, aA.w, aB.x, aB.y, aB.z, aB.w};
  float c8[8] = {cA.x, cA.y, cA.z, cA.w, cB.x, cB.y, cB.z, cB.w};
  const uint32x4* Y4 = (const uint32x4*)Y;   // row = 16 x uint4 (256 B)

  // self term (all quads read same row; quad 0 owns SKIP + init)
  uint32x4 sv = Y4[(size_t)n * 16 + l16];
  uint_t svp[4] = {sv.x, sv.y, sv.z, sv.w};
  float h[8];
#pragma unroll
  for (int j = 0; j < 4; ++j) {
    h[2 * j]     = fmaxf(fmaf(a8[2 * j],     f16l(svp[j]), c8[2 * j]), 0.0f);
    h[2 * j + 1] = fmaxf(fmaf(a8[2 * j + 1], f16h(svp[j]), c8[2 * j + 1]), 0.0f);
  }
  if (quad == 0) {
    if (smode == 1) {
      uint32x4 o = {pk16(h[0], h[1]), pk16(h[2], h[3]), pk16(h[4], h[5]), pk16(h[6], h[7])};
      ((uint32x4*)SKIP)[(size_t)n * 16 + l16] = o;
    } else if (smode == 2) {
      uint32x4 s = ((const uint32x4*)SKIP)[(size_t)n * 16 + l16];
      uint_t sp[4] = {s.x, s.y, s.z, s.w};
      uint_t op[4];
#pragma unroll
      for (int j = 0; j < 4; ++j)
        op[j] = pk16(f16l(sp[j]) + h[2 * j], f16h(sp[j]) + h[2 * j + 1]);
      uint32x4 o = {op[0], op[1], op[2], op[3]};
      ((uint32x4*)SKIP)[(size_t)n * 16 + l16] = o;
    }
  }
  float acc[8], acc2[8];
#pragma unroll
  for (int j = 0; j < 8; ++j) {
    acc[j] = (quad == 0) ? h[j] * e : 0.0f;
    acc2[j] = 0.0f;
  }
  int beg = rp[n], end = rp[n + 1];
  int p = beg;
  for (; p + 8 <= end; p += 8) {
    int s0 = colb[p + quad];
    int s1 = colb[p + 4 + quad];
    uint32x4 v0 = Y4[(size_t)s0 * 16 + l16];
    uint32x4 v1 = Y4[(size_t)s1 * 16 + l16];
    uint_t v0p[4] = {v0.x, v0.y, v0.z, v0.w};
    uint_t v1p[4] = {v1.x, v1.y, v1.z, v1.w};
#pragma unroll
    for (int j = 0; j < 4; ++j) {
      acc[2 * j]      += fmaxf(fmaf(a8[2 * j],     f16l(v0p[j]), c8[2 * j]), 0.0f);
      acc[2 * j + 1]  += fmaxf(fmaf(a8[2 * j + 1], f16h(v0p[j]), c8[2 * j + 1]), 0.0f);
      acc2[2 * j]     += fmaxf(fmaf(a8[2 * j],     f16l(v1p[j]), c8[2 * j]), 0.0f);
      acc2[2 * j + 1] += fmaxf(fmaf(a8[2 * j + 1], f16h(v1p[j]), c8[2 * j + 1]), 0.0f);
    }
  }
  if (p + 4 <= end) {
    int s = colb[p + quad];
    uint32x4 v = Y4[(size_t)s * 16 + l16];
    uint_t vp[4] = {v.x, v.y, v.z, v.w};
#pragma unroll
    for (int j = 0; j < 4; ++j) {
      acc[2 * j]     += fmaxf(fmaf(a8[2 * j],     f16l(vp[j]), c8[2 * j]), 0.0f);
      acc[2 * j + 1] += fmaxf(fmaf(a8[2 * j + 1], f16h(vp[j]), c8[2 * j + 1]), 0.0f);
    }
    p += 4;
  }
  if (p + quad < end) {   // remainder < 4: quad q takes edge p+q if it exists
    int s = colb[p + quad];
    uint32x4 v = Y4[(size_t)s * 16 + l16];
    uint_t vp[4] = {v.x, v.y, v.z, v.w};
#pragma unroll
    for (int j = 0; j < 4; ++j) {
      acc2[2 * j]     += fmaxf(fmaf(a8[2 * j],     f16l(vp[j]), c8[2 * j]), 0.0f);
      acc2[2 * j + 1] += fmaxf(fmaf(a8[2 * j + 1], f16h(vp[j]), c8[2 * j + 1]), 0.0f);
    }
  }
  uint_t op[4];
#pragma unroll
  for (int j = 0; j < 8; ++j) {
    float t = acc[j] + acc2[j];
    t += __shfl_xor(t, 16, 64);
    t += __shfl_xor(t, 32, 64);
    acc[j] = t;
  }
  if (quad == 0) {
#pragma unroll
    for (int j = 0; j < 4; ++j) op[j] = pk16(acc[2 * j], acc[2 * j + 1]);
    uint32x4 o = {op[0], op[1], op[2], op[3]};
    ((uint32x4*)Z)[(size_t)n * 16 + l16] = o;
  }
}

// ======== LDS-free fp16 MFMA GEMM — r24: 256-row tiles (4 row-frags/wave) ========
// r24: 391 blocks (was 782): halves stats-atomic count + cnt chain (24->12), each B
// fragment feeds 4 row-frags (B-load per MFMA halved). ~190 VGPR -> 2 blocks/CU; 391
// blocks still fully co-resident (512 slots). A-path = r23 packed-fp32 w/ fp32 BN params
// (r22 ERRATA: fp16-rounded pc = beta-sc*mu biases the normalized value; params MUST
// stay fp32, only the final activation rounds to fp16).
// MODE 0: a = A2u fp16 [M][128] direct (nt loads)
// MODE 1: a = relu(pa*x+pc), x = A2u fp16 (plain loads)
// MODE 2: a = 0.25*(SKIP fp16 + relu(pa*y+pc)), SKIP via (ushort*)A, y = A2u fp16
// MODE 3: a = (fp16)A, A fp32 [M][16], K=32 pad
// OUT 0: C fp32   OUT 1: C fp16 (plain — consumer reuses via cache)
template <int KTOT, int MODE, int OUT>
__global__ __launch_bounds__(256, 2) void gemm_mfma(
    const float* __restrict__ A, const ushort_t* __restrict__ A2u,
    const ushort_t* __restrict__ Bhi,
    const float* __restrict__ bias,
    const float* __restrict__ pa, const float* __restrict__ pc,
    void* __restrict__ Cv,
    float* __restrict__ gstat,
    float* __restrict__ aout, float* __restrict__ cout, int* __restrict__ cnt,
    const float* __restrict__ gamma, const float* __restrict__ beta,
    float invN, int M, int nb) {
  __shared__ float s_part[4][256];   // [wave][0..127]=sum, [128..255]=sumsq
  __shared__ int s_last;
  const int tid = threadIdx.x;
  const int w = tid >> 6;
  const int lane = tid & 63;
  const int ln = lane & 15;
  const int quad = lane >> 4;
  const int brow = blockIdx.x * 256;
  const int wbase = brow + (w << 6);

  int rr[4];
#pragma unroll
  for (int rt = 0; rt < 4; ++rt) {
    rr[rt] = wbase + (rt << 4) + ln;
    if (rr[rt] >= M) rr[rt] = M - 1;
  }

  f32x4 acc[4][8];
#pragma unroll
  for (int rt = 0; rt < 4; ++rt)
#pragma unroll
    for (int ct = 0; ct < 8; ++ct) acc[rt][ct] = (f32x4){0.0f, 0.0f, 0.0f, 0.0f};

  constexpr int KC = KTOT / 32;
  const f2_t zf2 = {0.0f, 0.0f};

#pragma unroll
  for (int kcl = 0; kcl < KC; ++kcl) {
    const int kb = (kcl << 5) + (quad << 3);
    f16x8 af[4];
    if constexpr (MODE == 0) {
#pragma unroll
      for (int rt = 0; rt < 4; ++rt)
        af[rt] = __builtin_bit_cast(f16x8, ntl_s8(A2u + (size_t)rr[rt] * 128 + kb));
    } else if constexpr (MODE == 1) {
      float4 p0 = *(const float4*)(pa + kb);
      float4 p1 = *(const float4*)(pa + kb + 4);
      float4 q0 = *(const float4*)(pc + kb);
      float4 q1 = *(const float4*)(pc + kb + 4);
      f2_t pp2[4] = {{p0.x, p0.y}, {p0.z, p0.w}, {p1.x, p1.y}, {p1.z, p1.w}};
      f2_t qq2[4] = {{q0.x, q0.y}, {q0.z, q0.w}, {q1.x, q1.y}, {q1.z, q1.w}};
#pragma unroll
      for (int rt = 0; rt < 4; ++rt) {
        uint32x4 xa = *(const uint32x4*)(A2u + (size_t)rr[rt] * 128 + kb);
        uint_t ua[4] = {xa.x, xa.y, xa.z, xa.w};
#pragma unroll
        for (int u = 0; u < 4; ++u) {
          f2_t ya = {f16l(ua[u]), f16h(ua[u])};
          f2_t ma = __builtin_elementwise_max(
              __builtin_elementwise_fma(pp2[u], ya, qq2[u]), zf2);
          af[rt][2 * u] = (_Float16)ma.x;
          af[rt][2 * u + 1] = (_Float16)ma.y;
        }
      }
    } else if constexpr (MODE == 2) {
      const ushort_t* Au = (const ushort_t*)A;   // SKIP fp16 (r21)
      float4 p0 = *(const float4*)(pa + kb);
      float4 p1 = *(const float4*)(pa + kb + 4);
      float4 q0 = *(const float4*)(pc + kb);
      float4 q1 = *(const float4*)(pc + kb + 4);
      f2_t pp2[4] = {{p0.x, p0.y}, {p0.z, p0.w}, {p1.x, p1.y}, {p1.z, p1.w}};
      f2_t qq2[4] = {{q0.x, q0.y}, {q0.z, q0.w}, {q1.x, q1.y}, {q1.z, q1.w}};
      const f2_t qf2 = {0.25f, 0.25f};
#pragma unroll
      for (int rt = 0; rt < 4; ++rt) {
        uint32x4 sa = *(const uint32x4*)(Au + (size_t)rr[rt] * 128 + kb);
        uint32x4 ya = *(const uint32x4*)(A2u + (size_t)rr[rt] * 128 + kb);
        uint_t uya[4] = {ya.x, ya.y, ya.z, ya.w};
        uint_t usa[4] = {sa.x, sa.y, sa.z, sa.w};
#pragma unroll
        for (int u = 0; u < 4; ++u) {
          f2_t y0 = {f16l(uya[u]), f16h(uya[u])};
          f2_t s0 = {f16l(usa[u]), f16h(usa[u])};
          f2_t m0 = __builtin_elementwise_max(
              __builtin_elementwise_fma(pp2[u], y0, qq2[u]), zf2);
          f2_t e0 = (s0 + m0) * qf2;
          af[rt][2 * u] = (_Float16)e0.x;
          af[rt][2 * u + 1] = (_Float16)e0.y;
        }
      }
    } else {  // MODE 3
      if (kb < 16) {
#pragma unroll
        for (int rt = 0; rt < 4; ++rt) {
          f32x4 a0 = ntl4(A + (size_t)rr[rt] * 16 + kb);
          f32x4 a1 = ntl4(A + (size_t)rr[rt] * 16 + kb + 4);
          float e0[8] = {a0.x, a0.y, a0.z, a0.w, a1.x, a1.y, a1.z, a1.w};
          af[rt] = pack8(e0);
        }
      } else {
#pragma unroll
        for (int rt = 0; rt < 4; ++rt)
#pragma unroll
          for (int j = 0; j < 8; ++j) af[rt][j] = (_Float16)0.0f;
      }
    }
    const ushort_t* bh_base = Bhi + (((size_t)(kcl << 9) + lane) << 3);
#pragma unroll
    for (int ct = 0; ct < 8; ++ct) {
      f16x8 bh = __builtin_bit_cast(f16x8, *(const short8*)(bh_base + (ct << 9)));
#pragma unroll
      for (int rt = 0; rt < 4; ++rt)
        acc[rt][ct] = __builtin_amdgcn_mfma_f32_16x16x32_f16(af[rt], bh, acc[rt][ct], 0, 0, 0);
    }
  }

  // ---- epilogue: bias, store, quad-shuffle stats ----
#pragma unroll
  for (int ct = 0; ct < 8; ++ct) {
    int col = (ct << 4) + ln;
    float bsc = bias[col];
    float csum = 0.0f, csq = 0.0f;
#pragma unroll
    for (int rt = 0; rt < 4; ++rt) {
#pragma unroll
      for (int i = 0; i < 4; ++i) {
        int row = wbase + (rt << 4) + (quad << 2) + i;
        if (row < M) {
          float y = acc[rt][ct][i] + bsc;
          csum += y; csq += y * y;
          if constexpr (OUT == 0) {
            ((float*)Cv)[(size_t)row * 128 + col] = y;
          } else {
            ((ushort_t*)Cv)[(size_t)row * 128 + col] = f2h(y);
          }
        }
      }
    }
    csum += __shfl_xor(csum, 16, 64);
    csum += __shfl_xor(csum, 32, 64);
    csq += __shfl_xor(csq, 16, 64);
    csq += __shfl_xor(csq, 32, 64);
    if (quad == 0) {
      s_part[w][col] = csum;
      s_part[w][128 + col] = csq;
    }
  }
  __syncthreads();
  const int cls = (int)(blockIdx.x & (NCLS - 1));
  {
    // one atomic per thread: ch 0..127 = sum, 128..255 = sumsq
    float v = s_part[0][tid] + s_part[1][tid] + s_part[2][tid] + s_part[3][tid];
    atomicAdd(&gstat[(cls << 8) + tid], v);
  }
  __syncthreads();   // drains vmcnt -> stats atomics complete
  if (tid == 0) {
    s_last = 0;
    int clsCnt = (nb >> 5) + ((cls < (nb & (NCLS - 1))) ? 1 : 0);
    int v = __hip_atomic_fetch_add(&cnt[cls], 1, __ATOMIC_RELAXED, __HIP_MEMORY_SCOPE_AGENT);
    if (v == clsCnt - 1) {   // last of this class -> bump master
      int vm = __hip_atomic_fetch_add(&cnt[NCLS], 1, __ATOMIC_RELAXED, __HIP_MEMORY_SCOPE_AGENT);
      if (vm == NCLS - 1) s_last = 1;
    }
  }
  __syncthreads();
  if (s_last && tid < 128) {
    float s = 0.0f, q = 0.0f;
#pragma unroll
    for (int c = 0; c < NCLS; ++c) {
      s += __hip_atomic_load(&gstat[(c << 8) + tid], __ATOMIC_RELAXED, __HIP_MEMORY_SCOPE_AGENT);
      q += __hip_atomic_load(&gstat[(c << 8) + 128 + tid], __ATOMIC_RELAXED,
                             __HIP_MEMORY_SCOPE_AGENT);
    }
    float mu = s * invN;
    float var = q * invN - mu * mu;
    float sc = gamma[tid] * rsqrtf(var + BN_EPS);
    aout[tid] = sc;
    cout[tid] = beta[tid] - sc * mu;
  }
}

// ============================ regressor head ============================
__global__ __launch_bounds__(256) void finaldot_kernel(
    const ushort_t* __restrict__ Y, const float* __restrict__ a, const float* __restrict__ c,
    const float* __restrict__ Wr2, const float* __restrict__ br2,
    float* __restrict__ out, int N) {
  int wv = threadIdx.x >> 6;
  int lane = threadIdx.x & 63;
  int n = blockIdx.x * 4 + wv;
  if (n >= N) return;
  uint_t yv = ((const uint_t*)Y)[(size_t)n * 64 + lane];
  int c0 = lane * 2;
  float s = fmaxf(fmaf(a[c0], f16l(yv), c[c0]), 0.0f) * Wr2[c0] +
            fmaxf(fmaf(a[c0 + 1], f16h(yv), c[c0 + 1]), 0.0f) * Wr2[c0 + 1];
  for (int off = 32; off > 0; off >>= 1) s += __shfl_down(s, off, 64);
  if (lane == 0) out[n] = 1.0f / (1.0f + expf(-(s + br2[0])));
}

// ============================ launch ============================
extern "C" void kernel_launch(void* const* d_in, const int* in_sizes, int n_in,
                              void* d_out, int out_size, void* d_ws, size_t ws_size,
                              hipStream_t stream) {
  const float* x     = (const float*)d_in[0];
  const int*   ei    = (const int*)d_in[1];
  const float* eps   = (const float*)d_in[2];
  const float* W1_0  = (const float*)d_in[3];
  const float* b1_0  = (const float*)d_in[4];
  const float* W1    = (const float*)d_in[5];
  const float* b1    = (const float*)d_in[6];
  const float* g_in  = (const float*)d_in[7];
  const float* be_in = (const float*)d_in[8];
  const float* W2    = (const float*)d_in[9];
  const float* b2    = (const float*)d_in[10];
  const float* g_out = (const float*)d_in[11];
  const float* be_out= (const float*)d_in[12];
  const float* Wr1   = (const float*)d_in[13];
  const float* br1   = (const float*)d_in[14];
  const float* gr    = (const float*)d_in[15];
  const float* ber   = (const float*)d_in[16];
  const float* Wr2   = (const float*)d_in[17];
  const float* br2   = (const float*)d_in[18];
  float* out = (float*)d_out;

  const int N = in_sizes[0] / IN_F;   // 100000
  const int E = in_sizes[1] / 2;      // 1600000
  const int* srcv = ei;
  const int* dstv = ei + E;
  const int nbk = (N + 511) >> 9;     // 196 buckets

  // workspace carve (SKIP region fp32-sized; holds L0 [N,16] fp32 temp, then fp16 skip)
  float* X0    = (float*)d_ws;                  // [N][128] fp32-sized (fp16 Z/H1/head)
  float* SKIP  = X0 + (size_t)N * HID;          // [N][128] region (fp16 skip since r21)
  ushort_t* YB = (ushort_t*)(SKIP + (size_t)N * HID);  // [N][128] fp16 Y (hot gather target)
  int* colb    = (int*)(YB + (size_t)N * HID);
  int* row_ptr = colb + E;
  int2* ebuf   = (int2*)(row_ptr + (N + 4));
  int* bucketCnt  = (int*)(ebuf + E);
  int* bucketBase = bucketCnt + 256;
  int* bucketCur  = bucketBase + 260;
  // arena: 17 slots x 8512 floats:
  //   [0..8191] gstat[32][256] | [8192..8319] SA | [8320..8447] SC
  //   [8448..8480] cnt[33] | pad to 8512
  float* arena = (float*)(bucketCur + 256);
  ushort_t* WB = (ushort_t*)(arena + 17 * 8512); // hi blob (fp16)
  ushort_t* X0u = (ushort_t*)X0;
  ushort_t* SKIPu = (ushort_t*)SKIP;

  hipMemsetAsync(bucketCnt, 0, sizeof(int) * 256, stream);
  hipMemsetAsync(arena, 0, sizeof(float) * 17 * 8512, stream);

  // CSR build (bucket sort)
  int nbE = (E + 2047) / 2048;
  bhist_kernel<<<nbE, 256, 0, stream>>>(dstv, bucketCnt, E, nbk);
  bscan_kernel<<<1, 256, 0, stream>>>(bucketCnt, bucketBase, bucketCur, row_ptr, N, E, nbk);
  bscatter_kernel<<<nbE, 256, 0, stream>>>(srcv, dstv, bucketCur, ebuf, E, nbk);
  bcsr_kernel<<<nbk, 256, 0, stream>>>(ebuf, bucketBase, row_ptr, colb, N);
  preconv_kernel<<<dim3(64, 17), 256, 0, stream>>>(W1_0, W1, W2, Wr1, WB);

  const int gg = (N + 255) / 256;   // r24: 256-row tiles (391 blocks)
  const float invN = 1.0f / (float)N;
#define SLOT(s) (arena + (s) * 8512)
#define SSTAT(s) SLOT(s)
#define SA(s)   (SLOT(s) + 8192)
#define SC(s)   (SLOT(s) + 8320)
#define SCNT(s) ((int*)(SLOT(s) + 8448))
#define WBH(g)  (WB + ((g) == 0 ? 0 : (8192 + (size_t)((g) - 1) * 32768)))

  // ---- layer 0 ----  agg16: x -> SKIP[N,16] fp32 temp; g0a: SKIP -> X0u fp16; g0b: X0u -> YB
  agg16_kernel<<<(N + 31) / 32, 256, 0, stream>>>(x, row_ptr, colb, eps, SKIP, N);
  gemm_mfma<32, 3, 1><<<gg, 256, 0, stream>>>(
      SKIP, nullptr, WBH(0), b1_0, nullptr, nullptr, X0u,
      SSTAT(0), SA(0), SC(0), SCNT(0), g_in, be_in, invN, N, gg);
  gemm_mfma<128, 1, 1><<<gg, 256, 0, stream>>>(
      nullptr, X0u, WBH(8), b2, SA(0), SC(0), YB,
      SSTAT(1), SA(1), SC(1), SCNT(1), g_out, be_out, invN, N, gg);
  // No SKIP memset: L=2's agg does a plain store (smode=1) covering all N*128 elements.

  // ---- layers 1..7 ----  agg: YB->X0u (fp16 Z); gemm1: X0u->X0u in place; gemm2: X0u->YB
  for (int L = 1; L < NLAYERS; ++L) {
    int sp = 2 * L - 1;
    int s0 = 2 * L, s1 = 2 * L + 1;
    // skip taps h_1,h_3,h_5 at L=2,4,6 (h_7 folded in regressor). First tap stores.
    int smode = ((L - 1) & 1) ? ((L == 2) ? 1 : 2) : 0;
    agg128_kernel<<<(N + 3) / 4, 256, 0, stream>>>(
        YB, SA(sp), SC(sp), row_ptr, colb, eps, L, (uint_t*)X0u, SKIPu, smode, N);
    gemm_mfma<128, 0, 1><<<gg, 256, 0, stream>>>(
        nullptr, X0u, WBH(L), b1 + (size_t)(L - 1) * HID, nullptr, nullptr, X0u,
        SSTAT(s0), SA(s0), SC(s0), SCNT(s0),
        g_in + (size_t)L * HID, be_in + (size_t)L * HID, invN, N, gg);
    gemm_mfma<128, 1, 1><<<gg, 256, 0, stream>>>(
        nullptr, X0u, WBH(8 + L), b2 + (size_t)L * HID, SA(s0), SC(s0), YB,
        SSTAT(s1), SA(s1), SC(s1), SCNT(s1),
        g_out + (size_t)L * HID, be_out + (size_t)L * HID, invN, N, gg);
  }
  // Y7 in YB (fp16), slot 15 holds its outer-BN params

  // ---- regressor: op = 0.25*(SKIP fp16 + relu(a7*Y7+c7)); head output fp16 into X0u ----
  gemm_mfma<128, 2, 1><<<gg, 256, 0, stream>>>(
      (const float*)SKIPu, YB, WBH(16), br1, SA(15), SC(15), X0u,
      SSTAT(16), SA(16), SC(16), SCNT(16), gr, ber, invN, N, gg);
  finaldot_kernel<<<(N + 3) / 4, 256, 0, stream>>>(X0u, SA(16), SC(16), Wr2, br2, out, N);
#undef SLOT
#undef SSTAT
#undef SA
#undef SC
#undef SCNT
#undef WBH
}

// Round 12
// 1124.538 us; speedup vs baseline: 1.0405x; 1.0405x over previous
//
#include <hip/hip_runtime.h>
#include <hip/hip_bf16.h>

#define NNODES 100000
#define NEDGES 1600000
#define IN_F 16
#define HID 128
#define NLAYERS 8
#define BN_EPS 1e-5f
#define BLOBSZ 532480   // ushorts per blob: 8192 + 16*32768 (hi-only since r15)
#define NCLS 32         // r19: 32-way split stats

typedef __attribute__((ext_vector_type(8))) short short8;
typedef __attribute__((ext_vector_type(8))) _Float16 f16x8;
typedef __attribute__((ext_vector_type(2))) float f2_t;
typedef __attribute__((ext_vector_type(4))) float f32x4;
typedef __attribute__((ext_vector_type(4))) unsigned int uint32x4;
typedef unsigned short ushort_t;
typedef unsigned int uint_t;

// ---- fp16 helpers (r14: whole activation chain fp16) ----
__device__ __forceinline__ float f16l(uint_t u) {
  return (float)__builtin_bit_cast(_Float16, (ushort_t)(u & 0xFFFFu));
}
__device__ __forceinline__ float f16h(uint_t u) {
  return (float)__builtin_bit_cast(_Float16, (ushort_t)(u >> 16));
}
__device__ __forceinline__ ushort_t f2h(float f) {
  return __builtin_bit_cast(ushort_t, (_Float16)f);
}
__device__ __forceinline__ uint_t pk16(float x, float y) {
  return (uint_t)f2h(x) | ((uint_t)f2h(y) << 16);
}
__device__ __forceinline__ f16x8 pack8(const float* v) {
  f16x8 r;
#pragma unroll
  for (int j = 0; j < 8; ++j) r[j] = (_Float16)v[j];
  return r;
}

// nontemporal helpers (streams with no reuse; YB/X0u stay cached for reuse)
__device__ __forceinline__ f32x4 ntl4(const float* p) {
  return __builtin_nontemporal_load((const f32x4*)p);
}
__device__ __forceinline__ short8 ntl_s8(const ushort_t* p) {
  return __builtin_nontemporal_load((const short8*)p);
}

// ===================== CSR build: 2-level bucket sort (r8 win) =====================
__global__ __launch_bounds__(256) void bhist_kernel(
    const int* __restrict__ dst, int* __restrict__ bucketCnt, int E, int nbk) {
  __shared__ int cnt[256];
  int t = threadIdx.x;
  cnt[t] = 0;
  __syncthreads();
  int base = blockIdx.x * 2048 + t * 8;
#pragma unroll
  for (int j = 0; j < 8; ++j) {
    int i = base + j;
    if (i < E) atomicAdd(&cnt[dst[i] >> 9], 1);
  }
  __syncthreads();
  if (t < nbk && cnt[t]) atomicAdd(&bucketCnt[t], cnt[t]);
}

__global__ void bscan_kernel(const int* __restrict__ bucketCnt, int* __restrict__ bucketBase,
                             int* __restrict__ bucketCur, int* __restrict__ row_ptr,
                             int N, int E, int nbk) {
  __shared__ int s[256];
  int t = threadIdx.x;
  s[t] = (t < nbk) ? bucketCnt[t] : 0;
  __syncthreads();
  for (int off = 1; off < 256; off <<= 1) {
    int v = (t >= off) ? s[t - off] : 0;
    __syncthreads();
    s[t] += v;
    __syncthreads();
  }
  int excl = (t == 0) ? 0 : s[t - 1];
  if (t < nbk) { bucketBase[t] = excl; bucketCur[t] = excl; }
  if (t == nbk) bucketBase[t] = E;
  if (t == 0) row_ptr[N] = E;
}

__global__ __launch_bounds__(256) void bscatter_kernel(
    const int* __restrict__ src, const int* __restrict__ dst,
    int* __restrict__ bucketCur, int2* __restrict__ ebuf, int E, int nbk) {
  __shared__ int cnt[256];
  __shared__ int base_l[256];
  int t = threadIdx.x;
  cnt[t] = 0;
  __syncthreads();
  int base = blockIdx.x * 2048 + t * 8;
  int bj[8], lr[8], dj[8], sj[8];
#pragma unroll
  for (int j = 0; j < 8; ++j) {
    int i = base + j;
    if (i < E) {
      dj[j] = dst[i];
      sj[j] = src[i];
      bj[j] = dj[j] >> 9;
      lr[j] = atomicAdd(&cnt[bj[j]], 1);
    } else bj[j] = -1;
  }
  __syncthreads();
  if (t < nbk) base_l[t] = cnt[t] ? atomicAdd(&bucketCur[t], cnt[t]) : 0;
  __syncthreads();
#pragma unroll
  for (int j = 0; j < 8; ++j)
    if (bj[j] >= 0) ebuf[base_l[bj[j]] + lr[j]] = make_int2(dj[j], sj[j]);
}

__global__ __launch_bounds__(256) void bcsr_kernel(
    const int2* __restrict__ ebuf, const int* __restrict__ bucketBase,
    int* __restrict__ row_ptr, int* __restrict__ colb, int N) {
  __shared__ int h[512];
  __shared__ int cur[512];
  __shared__ int s2[256];
  int b = blockIdx.x, t = threadIdx.x;
  int beg = bucketBase[b], end = bucketBase[b + 1];
  h[t] = 0; h[t + 256] = 0;
  __syncthreads();
  for (int p = beg + t; p < end; p += 256) atomicAdd(&h[ebuf[p].x & 511], 1);
  __syncthreads();
  s2[t] = h[2 * t] + h[2 * t + 1];
  __syncthreads();
  for (int off = 1; off < 256; off <<= 1) {
    int v = (t >= off) ? s2[t - off] : 0;
    __syncthreads();
    s2[t] += v;
    __syncthreads();
  }
  int ep = (t == 0) ? 0 : s2[t - 1];
  cur[2 * t] = ep;
  cur[2 * t + 1] = ep + h[2 * t];
  int dg = (b << 9) + 2 * t;
  if (dg < N) row_ptr[dg] = beg + cur[2 * t];
  if (dg + 1 < N) row_ptr[dg + 1] = beg + cur[2 * t + 1];
  __syncthreads();
  for (int p = beg + t; p < end; p += 256) {
    int2 e2 = ebuf[p];
    int pos = beg + atomicAdd(&cur[e2.x & 511], 1);
    colb[pos] = e2.y;
  }
}

// =================== weight pre-convert: fp16 MFMA-frag blob (hi only, r15) ===================
__global__ void preconv_kernel(const float* __restrict__ W1_0, const float* __restrict__ W1,
                               const float* __restrict__ W2, const float* __restrict__ Wr1,
                               ushort_t* __restrict__ WB) {
  int g = blockIdx.y;
  int e = blockIdx.x * 256 + threadIdx.x;
  int KP = (g == 0) ? 32 : 128;
  if (e >= KP * 128) return;
  int k = e >> 7, n = e & 127;
  float v;
  if (g == 0) v = (k < 16) ? W1_0[k * 128 + n] : 0.0f;
  else if (g <= 7) v = W1[(size_t)(g - 1) * 16384 + e];
  else if (g <= 15) v = W2[(size_t)(g - 8) * 16384 + e];
  else v = Wr1[e];
  size_t base = (g == 0) ? 0 : (8192 + (size_t)(g - 1) * 32768);
  int unit = ((k >> 5) << 9) + ((n >> 4) << 6) + (n & 15) + (((k >> 3) & 3) << 4);
  WB[base + (size_t)unit * 8 + (k & 7)] = __builtin_bit_cast(ushort_t, (_Float16)v);
}

// ============================ layer-0 aggregation (F=16, fp32) ============================
__global__ __launch_bounds__(256) void agg16_kernel(
    const float* __restrict__ X, const int* __restrict__ rp, const int* __restrict__ colb,
    const float* __restrict__ eps, float* __restrict__ Z, int N) {
  int g = threadIdx.x >> 3;
  int l = threadIdx.x & 7;
  int n = blockIdx.x * 32 + g;
  if (n >= N) return;
  float e = 1.0f + eps[0];
  const float2* X2 = (const float2*)X;
  float2 self = X2[(size_t)n * 8 + l];
  float2 acc = make_float2(self.x * e, self.y * e);
  float2 acc2 = make_float2(0.0f, 0.0f);
  int beg = rp[n], end = rp[n + 1];
  int p = beg;
  for (; p + 4 <= end; p += 4) {
    int s0 = colb[p], s1 = colb[p + 1], s2 = colb[p + 2], s3 = colb[p + 3];
    float2 v0 = X2[(size_t)s0 * 8 + l];
    float2 v1 = X2[(size_t)s1 * 8 + l];
    float2 v2 = X2[(size_t)s2 * 8 + l];
    float2 v3 = X2[(size_t)s3 * 8 + l];
    acc.x += v0.x; acc.y += v0.y;
    acc2.x += v1.x; acc2.y += v1.y;
    acc.x += v2.x; acc.y += v2.y;
    acc2.x += v3.x; acc2.y += v3.y;
  }
  for (; p < end; ++p) {
    int s = colb[p];
    float2 v = X2[(size_t)s * 8 + l];
    acc.x += v.x; acc.y += v.y;
  }
  acc.x += acc2.x; acc.y += acc2.y;
  ((float2*)Z)[(size_t)n * 8 + l] = acc;
}

// layers 1..7 aggregation — r21 scalar quad-gather (measured floor 73.0 us; r23 packed
// form and r24 verified this is the best body). smode: 0 none, 1 SKIP store, 2 SKIP +=.
__global__ __launch_bounds__(256) void agg128_kernel(
    const ushort_t* __restrict__ Y, const float* __restrict__ av, const float* __restrict__ cv,
    const int* __restrict__ rp, const int* __restrict__ colb,
    const float* __restrict__ eps, int layer, uint_t* __restrict__ Z,
    ushort_t* __restrict__ SKIP, int smode, int N) {
  int wv = threadIdx.x >> 6;
  int lane = threadIdx.x & 63;
  int quad = lane >> 4;    // 0..3: which edge of a 4-group this lane serves
  int l16 = lane & 15;     // position within the 256 B row
  int n = blockIdx.x * 4 + wv;
  if (n >= N) return;
  float e = 1.0f + eps[layer];
  // 8 channels per lane: cols l16*8 .. l16*8+7
  float4 aA = *(const float4*)(av + l16 * 8);
  float4 aB = *(const float4*)(av + l16 * 8 + 4);
  float4 cA = *(const float4*)(cv + l16 * 8);
  float4 cB = *(const float4*)(cv + l16 * 8 + 4);
  float a8[8] = {aA.x, aA.y, aA.z, aA.w, aB.x, aB.y, aB.z, aB.w};
  float c8[8] = {cA.x, cA.y, cA.z, cA.w, cB.x, cB.y, cB.z, cB.w};
  const uint32x4* Y4 = (const uint32x4*)Y;   // row = 16 x uint4 (256 B)

  // self term (all quads read same row; quad 0 owns SKIP + init)
  uint32x4 sv = Y4[(size_t)n * 16 + l16];
  uint_t svp[4] = {sv.x, sv.y, sv.z, sv.w};
  float h[8];
#pragma unroll
  for (int j = 0; j < 4; ++j) {
    h[2 * j]     = fmaxf(fmaf(a8[2 * j],     f16l(svp[j]), c8[2 * j]), 0.0f);
    h[2 * j + 1] = fmaxf(fmaf(a8[2 * j + 1], f16h(svp[j]), c8[2 * j + 1]), 0.0f);
  }
  if (quad == 0) {
    if (smode == 1) {
      uint32x4 o = {pk16(h[0], h[1]), pk16(h[2], h[3]), pk16(h[4], h[5]), pk16(h[6], h[7])};
      ((uint32x4*)SKIP)[(size_t)n * 16 + l16] = o;
    } else if (smode == 2) {
      uint32x4 s = ((const uint32x4*)SKIP)[(size_t)n * 16 + l16];
      uint_t sp[4] = {s.x, s.y, s.z, s.w};
      uint_t op[4];
#pragma unroll
      for (int j = 0; j < 4; ++j)
        op[j] = pk16(f16l(sp[j]) + h[2 * j], f16h(sp[j]) + h[2 * j + 1]);
      uint32x4 o = {op[0], op[1], op[2], op[3]};
      ((uint32x4*)SKIP)[(size_t)n * 16 + l16] = o;
    }
  }
  float acc[8], acc2[8];
#pragma unroll
  for (int j = 0; j < 8; ++j) {
    acc[j] = (quad == 0) ? h[j] * e : 0.0f;
    acc2[j] = 0.0f;
  }
  int beg = rp[n], end = rp[n + 1];
  int p = beg;
  for (; p + 8 <= end; p += 8) {
    int s0 = colb[p + quad];
    int s1 = colb[p + 4 + quad];
    uint32x4 v0 = Y4[(size_t)s0 * 16 + l16];
    uint32x4 v1 = Y4[(size_t)s1 * 16 + l16];
    uint_t v0p[4] = {v0.x, v0.y, v0.z, v0.w};
    uint_t v1p[4] = {v1.x, v1.y, v1.z, v1.w};
#pragma unroll
    for (int j = 0; j < 4; ++j) {
      acc[2 * j]      += fmaxf(fmaf(a8[2 * j],     f16l(v0p[j]), c8[2 * j]), 0.0f);
      acc[2 * j + 1]  += fmaxf(fmaf(a8[2 * j + 1], f16h(v0p[j]), c8[2 * j + 1]), 0.0f);
      acc2[2 * j]     += fmaxf(fmaf(a8[2 * j],     f16l(v1p[j]), c8[2 * j]), 0.0f);
      acc2[2 * j + 1] += fmaxf(fmaf(a8[2 * j + 1], f16h(v1p[j]), c8[2 * j + 1]), 0.0f);
    }
  }
  if (p + 4 <= end) {
    int s = colb[p + quad];
    uint32x4 v = Y4[(size_t)s * 16 + l16];
    uint_t vp[4] = {v.x, v.y, v.z, v.w};
#pragma unroll
    for (int j = 0; j < 4; ++j) {
      acc[2 * j]     += fmaxf(fmaf(a8[2 * j],     f16l(vp[j]), c8[2 * j]), 0.0f);
      acc[2 * j + 1] += fmaxf(fmaf(a8[2 * j + 1], f16h(vp[j]), c8[2 * j + 1]), 0.0f);
    }
    p += 4;
  }
  if (p + quad < end) {   // remainder < 4: quad q takes edge p+q if it exists
    int s = colb[p + quad];
    uint32x4 v = Y4[(size_t)s * 16 + l16];
    uint_t vp[4] = {v.x, v.y, v.z, v.w};
#pragma unroll
    for (int j = 0; j < 4; ++j) {
      acc2[2 * j]     += fmaxf(fmaf(a8[2 * j],     f16l(vp[j]), c8[2 * j]), 0.0f);
      acc2[2 * j + 1] += fmaxf(fmaf(a8[2 * j + 1], f16h(vp[j]), c8[2 * j + 1]), 0.0f);
    }
  }
  uint_t op[4];
#pragma unroll
  for (int j = 0; j < 8; ++j) {
    float t = acc[j] + acc2[j];
    t += __shfl_xor(t, 16, 64);
    t += __shfl_xor(t, 32, 64);
    acc[j] = t;
  }
  if (quad == 0) {
#pragma unroll
    for (int j = 0; j < 4; ++j) op[j] = pk16(acc[2 * j], acc[2 * j + 1]);
    uint32x4 o = {op[0], op[1], op[2], op[3]};
    ((uint32x4*)Z)[(size_t)n * 16 + l16] = o;
  }
}

// ======== LDS-free fp16 MFMA GEMM — r25 = r23 exact (128-row tiles, measured best) ========
// Tile bracket closed: 64-row (r13) worse, 256-row (r24, 2 blk/CU) worse; 128-row + 4 blk/CU
// is the optimum. A-path: packed-fp32 with fp32 BN params (r22 ERRATA: fp16-rounded
// pc = beta-sc*mu biases the normalized value; params stay fp32, only the final
// activation rounds to fp16). r19 stats: 32-way split, 1 atomic/thread, hier counter.
// MODE 0: a = A2u fp16 [M][128] direct (nt loads)
// MODE 1: a = relu(pa*x+pc), x = A2u fp16 (plain loads)
// MODE 2: a = 0.25*(SKIP fp16 + relu(pa*y+pc)), SKIP via (ushort*)A, y = A2u fp16
// MODE 3: a = (fp16)A, A fp32 [M][16], K=32 pad
// OUT 0: C fp32   OUT 1: C fp16 (plain — consumer reuses via cache)
template <int KTOT, int MODE, int OUT>
__global__ __launch_bounds__(256, 4) void gemm_mfma(
    const float* __restrict__ A, const ushort_t* __restrict__ A2u,
    const ushort_t* __restrict__ Bhi,
    const float* __restrict__ bias,
    const float* __restrict__ pa, const float* __restrict__ pc,
    void* __restrict__ Cv,
    float* __restrict__ gstat,
    float* __restrict__ aout, float* __restrict__ cout, int* __restrict__ cnt,
    const float* __restrict__ gamma, const float* __restrict__ beta,
    float invN, int M, int nb) {
  __shared__ float s_part[4][256];   // [wave][0..127]=sum, [128..255]=sumsq
  __shared__ int s_last;
  const int tid = threadIdx.x;
  const int w = tid >> 6;
  const int lane = tid & 63;
  const int ln = lane & 15;
  const int quad = lane >> 4;
  const int brow = blockIdx.x * 128;

  int r0 = brow + (w << 5) + ln;       if (r0 >= M) r0 = M - 1;
  int r1 = brow + (w << 5) + 16 + ln;  if (r1 >= M) r1 = M - 1;

  f32x4 acc[2][8];
#pragma unroll
  for (int rt = 0; rt < 2; ++rt)
#pragma unroll
    for (int ct = 0; ct < 8; ++ct) acc[rt][ct] = (f32x4){0.0f, 0.0f, 0.0f, 0.0f};

  constexpr int KC = KTOT / 32;
  const f2_t zf2 = {0.0f, 0.0f};

#pragma unroll
  for (int kcl = 0; kcl < KC; ++kcl) {
    const int kb = (kcl << 5) + (quad << 3);
    f16x8 af0, af1;
    if constexpr (MODE == 0) {
      af0 = __builtin_bit_cast(f16x8, ntl_s8(A2u + (size_t)r0 * 128 + kb));
      af1 = __builtin_bit_cast(f16x8, ntl_s8(A2u + (size_t)r1 * 128 + kb));
    } else if constexpr (MODE == 1) {
      uint32x4 xa = *(const uint32x4*)(A2u + (size_t)r0 * 128 + kb);
      uint32x4 xb = *(const uint32x4*)(A2u + (size_t)r1 * 128 + kb);
      float4 p0 = *(const float4*)(pa + kb);
      float4 p1 = *(const float4*)(pa + kb + 4);
      float4 q0 = *(const float4*)(pc + kb);
      float4 q1 = *(const float4*)(pc + kb + 4);
      f2_t pp2[4] = {{p0.x, p0.y}, {p0.z, p0.w}, {p1.x, p1.y}, {p1.z, p1.w}};
      f2_t qq2[4] = {{q0.x, q0.y}, {q0.z, q0.w}, {q1.x, q1.y}, {q1.z, q1.w}};
      uint_t ua[4] = {xa.x, xa.y, xa.z, xa.w};
      uint_t ub[4] = {xb.x, xb.y, xb.z, xb.w};
#pragma unroll
      for (int u = 0; u < 4; ++u) {
        f2_t ya = {f16l(ua[u]), f16h(ua[u])};
        f2_t yb = {f16l(ub[u]), f16h(ub[u])};
        f2_t ma = __builtin_elementwise_max(
            __builtin_elementwise_fma(pp2[u], ya, qq2[u]), zf2);
        f2_t mb = __builtin_elementwise_max(
            __builtin_elementwise_fma(pp2[u], yb, qq2[u]), zf2);
        af0[2 * u] = (_Float16)ma.x; af0[2 * u + 1] = (_Float16)ma.y;
        af1[2 * u] = (_Float16)mb.x; af1[2 * u + 1] = (_Float16)mb.y;
      }
    } else if constexpr (MODE == 2) {
      const ushort_t* Au = (const ushort_t*)A;   // SKIP fp16 (r21)
      uint32x4 sa = *(const uint32x4*)(Au + (size_t)r0 * 128 + kb);
      uint32x4 sb = *(const uint32x4*)(Au + (size_t)r1 * 128 + kb);
      uint32x4 ya = *(const uint32x4*)(A2u + (size_t)r0 * 128 + kb);
      uint32x4 yb = *(const uint32x4*)(A2u + (size_t)r1 * 128 + kb);
      float4 p0 = *(const float4*)(pa + kb);
      float4 p1 = *(const float4*)(pa + kb + 4);
      float4 q0 = *(const float4*)(pc + kb);
      float4 q1 = *(const float4*)(pc + kb + 4);
      f2_t pp2[4] = {{p0.x, p0.y}, {p0.z, p0.w}, {p1.x, p1.y}, {p1.z, p1.w}};
      f2_t qq2[4] = {{q0.x, q0.y}, {q0.z, q0.w}, {q1.x, q1.y}, {q1.z, q1.w}};
      const f2_t qf2 = {0.25f, 0.25f};
      uint_t uya[4] = {ya.x, ya.y, ya.z, ya.w};
      uint_t uyb[4] = {yb.x, yb.y, yb.z, yb.w};
      uint_t usa[4] = {sa.x, sa.y, sa.z, sa.w};
      uint_t usb[4] = {sb.x, sb.y, sb.z, sb.w};
#pragma unroll
      for (int u = 0; u < 4; ++u) {
        f2_t y0 = {f16l(uya[u]), f16h(uya[u])};
        f2_t y1 = {f16l(uyb[u]), f16h(uyb[u])};
        f2_t s0 = {f16l(usa[u]), f16h(usa[u])};
        f2_t s1 = {f16l(usb[u]), f16h(usb[u])};
        f2_t m0 = __builtin_elementwise_max(
            __builtin_elementwise_fma(pp2[u], y0, qq2[u]), zf2);
        f2_t m1 = __builtin_elementwise_max(
            __builtin_elementwise_fma(pp2[u], y1, qq2[u]), zf2);
        f2_t e0 = (s0 + m0) * qf2;
        f2_t e1 = (s1 + m1) * qf2;
        af0[2 * u] = (_Float16)e0.x; af0[2 * u + 1] = (_Float16)e0.y;
        af1[2 * u] = (_Float16)e1.x; af1[2 * u + 1] = (_Float16)e1.y;
      }
    } else {  // MODE 3
      if (kb < 16) {
        f32x4 a0 = ntl4(A + (size_t)r0 * 16 + kb);
        f32x4 a1 = ntl4(A + (size_t)r0 * 16 + kb + 4);
        f32x4 b0 = ntl4(A + (size_t)r1 * 16 + kb);
        f32x4 b1 = ntl4(A + (size_t)r1 * 16 + kb + 4);
        float e0[8] = {a0.x, a0.y, a0.z, a0.w, a1.x, a1.y, a1.z, a1.w};
        float e1[8] = {b0.x, b0.y, b0.z, b0.w, b1.x, b1.y, b1.z, b1.w};
        af0 = pack8(e0);
        af1 = pack8(e1);
      } else {
#pragma unroll
        for (int j = 0; j < 8; ++j) { af0[j] = (_Float16)0.0f; af1[j] = (_Float16)0.0f; }
      }
    }
    const ushort_t* bh_base = Bhi + (((size_t)(kcl << 9) + lane) << 3);
#pragma unroll
    for (int ct = 0; ct < 8; ++ct) {
      f16x8 bh = __builtin_bit_cast(f16x8, *(const short8*)(bh_base + (ct << 9)));
      acc[0][ct] = __builtin_amdgcn_mfma_f32_16x16x32_f16(af0, bh, acc[0][ct], 0, 0, 0);
      acc[1][ct] = __builtin_amdgcn_mfma_f32_16x16x32_f16(af1, bh, acc[1][ct], 0, 0, 0);
    }
  }

  // ---- epilogue: bias, store, quad-shuffle stats ----
#pragma unroll
  for (int ct = 0; ct < 8; ++ct) {
    int col = (ct << 4) + ln;
    float bsc = bias[col];
    float csum = 0.0f, csq = 0.0f;
#pragma unroll
    for (int rt = 0; rt < 2; ++rt) {
#pragma unroll
      for (int i = 0; i < 4; ++i) {
        int row = brow + (w << 5) + (rt << 4) + (quad << 2) + i;
        if (row < M) {
          float y = acc[rt][ct][i] + bsc;
          csum += y; csq += y * y;
          if constexpr (OUT == 0) {
            ((float*)Cv)[(size_t)row * 128 + col] = y;
          } else {
            ((ushort_t*)Cv)[(size_t)row * 128 + col] = f2h(y);
          }
        }
      }
    }
    csum += __shfl_xor(csum, 16, 64);
    csum += __shfl_xor(csum, 32, 64);
    csq += __shfl_xor(csq, 16, 64);
    csq += __shfl_xor(csq, 32, 64);
    if (quad == 0) {
      s_part[w][col] = csum;
      s_part[w][128 + col] = csq;
    }
  }
  __syncthreads();
  const int cls = (int)(blockIdx.x & (NCLS - 1));
  {
    // one atomic per thread: ch 0..127 = sum, 128..255 = sumsq
    float v = s_part[0][tid] + s_part[1][tid] + s_part[2][tid] + s_part[3][tid];
    atomicAdd(&gstat[(cls << 8) + tid], v);
  }
  __syncthreads();   // drains vmcnt -> stats atomics complete
  if (tid == 0) {
    s_last = 0;
    int clsCnt = (nb >> 5) + ((cls < (nb & (NCLS - 1))) ? 1 : 0);
    int v = __hip_atomic_fetch_add(&cnt[cls], 1, __ATOMIC_RELAXED, __HIP_MEMORY_SCOPE_AGENT);
    if (v == clsCnt - 1) {   // last of this class -> bump master
      int vm = __hip_atomic_fetch_add(&cnt[NCLS], 1, __ATOMIC_RELAXED, __HIP_MEMORY_SCOPE_AGENT);
      if (vm == NCLS - 1) s_last = 1;
    }
  }
  __syncthreads();
  if (s_last && tid < 128) {
    float s = 0.0f, q = 0.0f;
#pragma unroll
    for (int c = 0; c < NCLS; ++c) {
      s += __hip_atomic_load(&gstat[(c << 8) + tid], __ATOMIC_RELAXED, __HIP_MEMORY_SCOPE_AGENT);
      q += __hip_atomic_load(&gstat[(c << 8) + 128 + tid], __ATOMIC_RELAXED,
                             __HIP_MEMORY_SCOPE_AGENT);
    }
    float mu = s * invN;
    float var = q * invN - mu * mu;
    float sc = gamma[tid] * rsqrtf(var + BN_EPS);
    aout[tid] = sc;
    cout[tid] = beta[tid] - sc * mu;
  }
}

// ============================ regressor head ============================
__global__ __launch_bounds__(256) void finaldot_kernel(
    const ushort_t* __restrict__ Y, const float* __restrict__ a, const float* __restrict__ c,
    const float* __restrict__ Wr2, const float* __restrict__ br2,
    float* __restrict__ out, int N) {
  int wv = threadIdx.x >> 6;
  int lane = threadIdx.x & 63;
  int n = blockIdx.x * 4 + wv;
  if (n >= N) return;
  uint_t yv = ((const uint_t*)Y)[(size_t)n * 64 + lane];
  int c0 = lane * 2;
  float s = fmaxf(fmaf(a[c0], f16l(yv), c[c0]), 0.0f) * Wr2[c0] +
            fmaxf(fmaf(a[c0 + 1], f16h(yv), c[c0 + 1]), 0.0f) * Wr2[c0 + 1];
  for (int off = 32; off > 0; off >>= 1) s += __shfl_down(s, off, 64);
  if (lane == 0) out[n] = 1.0f / (1.0f + expf(-(s + br2[0])));
}

// ============================ launch ============================
extern "C" void kernel_launch(void* const* d_in, const int* in_sizes, int n_in,
                              void* d_out, int out_size, void* d_ws, size_t ws_size,
                              hipStream_t stream) {
  const float* x     = (const float*)d_in[0];
  const int*   ei    = (const int*)d_in[1];
  const float* eps   = (const float*)d_in[2];
  const float* W1_0  = (const float*)d_in[3];
  const float* b1_0  = (const float*)d_in[4];
  const float* W1    = (const float*)d_in[5];
  const float* b1    = (const float*)d_in[6];
  const float* g_in  = (const float*)d_in[7];
  const float* be_in = (const float*)d_in[8];
  const float* W2    = (const float*)d_in[9];
  const float* b2    = (const float*)d_in[10];
  const float* g_out = (const float*)d_in[11];
  const float* be_out= (const float*)d_in[12];
  const float* Wr1   = (const float*)d_in[13];
  const float* br1   = (const float*)d_in[14];
  const float* gr    = (const float*)d_in[15];
  const float* ber   = (const float*)d_in[16];
  const float* Wr2   = (const float*)d_in[17];
  const float* br2   = (const float*)d_in[18];
  float* out = (float*)d_out;

  const int N = in_sizes[0] / IN_F;   // 100000
  const int E = in_sizes[1] / 2;      // 1600000
  const int* srcv = ei;
  const int* dstv = ei + E;
  const int nbk = (N + 511) >> 9;     // 196 buckets

  // workspace carve (SKIP region fp32-sized; holds L0 [N,16] fp32 temp, then fp16 skip)
  float* X0    = (float*)d_ws;                  // [N][128] fp32-sized (fp16 Z/H1/head)
  float* SKIP  = X0 + (size_t)N * HID;          // [N][128] region (fp16 skip since r21)
  ushort_t* YB = (ushort_t*)(SKIP + (size_t)N * HID);  // [N][128] fp16 Y (hot gather target)
  int* colb    = (int*)(YB + (size_t)N * HID);
  int* row_ptr = colb + E;
  int2* ebuf   = (int2*)(row_ptr + (N + 4));
  int* bucketCnt  = (int*)(ebuf + E);
  int* bucketBase = bucketCnt + 256;
  int* bucketCur  = bucketBase + 260;
  // arena: 17 slots x 8512 floats:
  //   [0..8191] gstat[32][256] | [8192..8319] SA | [8320..8447] SC
  //   [8448..8480] cnt[33] | pad to 8512
  float* arena = (float*)(bucketCur + 256);
  ushort_t* WB = (ushort_t*)(arena + 17 * 8512); // hi blob (fp16)
  ushort_t* X0u = (ushort_t*)X0;
  ushort_t* SKIPu = (ushort_t*)SKIP;

  hipMemsetAsync(bucketCnt, 0, sizeof(int) * 256, stream);
  hipMemsetAsync(arena, 0, sizeof(float) * 17 * 8512, stream);

  // CSR build (bucket sort)
  int nbE = (E + 2047) / 2048;
  bhist_kernel<<<nbE, 256, 0, stream>>>(dstv, bucketCnt, E, nbk);
  bscan_kernel<<<1, 256, 0, stream>>>(bucketCnt, bucketBase, bucketCur, row_ptr, N, E, nbk);
  bscatter_kernel<<<nbE, 256, 0, stream>>>(srcv, dstv, bucketCur, ebuf, E, nbk);
  bcsr_kernel<<<nbk, 256, 0, stream>>>(ebuf, bucketBase, row_ptr, colb, N);
  preconv_kernel<<<dim3(64, 17), 256, 0, stream>>>(W1_0, W1, W2, Wr1, WB);

  const int gg = (N + 127) / 128;   // 128-row tiles (r25: bracket-confirmed optimum)
  const float invN = 1.0f / (float)N;
#define SLOT(s) (arena + (s) * 8512)
#define SSTAT(s) SLOT(s)
#define SA(s)   (SLOT(s) + 8192)
#define SC(s)   (SLOT(s) + 8320)
#define SCNT(s) ((int*)(SLOT(s) + 8448))
#define WBH(g)  (WB + ((g) == 0 ? 0 : (8192 + (size_t)((g) - 1) * 32768)))

  // ---- layer 0 ----  agg16: x -> SKIP[N,16] fp32 temp; g0a: SKIP -> X0u fp16; g0b: X0u -> YB
  agg16_kernel<<<(N + 31) / 32, 256, 0, stream>>>(x, row_ptr, colb, eps, SKIP, N);
  gemm_mfma<32, 3, 1><<<gg, 256, 0, stream>>>(
      SKIP, nullptr, WBH(0), b1_0, nullptr, nullptr, X0u,
      SSTAT(0), SA(0), SC(0), SCNT(0), g_in, be_in, invN, N, gg);
  gemm_mfma<128, 1, 1><<<gg, 256, 0, stream>>>(
      nullptr, X0u, WBH(8), b2, SA(0), SC(0), YB,
      SSTAT(1), SA(1), SC(1), SCNT(1), g_out, be_out, invN, N, gg);
  // No SKIP memset: L=2's agg does a plain store (smode=1) covering all N*128 elements.

  // ---- layers 1..7 ----  agg: YB->X0u (fp16 Z); gemm1: X0u->X0u in place; gemm2: X0u->YB
  for (int L = 1; L < NLAYERS; ++L) {
    int sp = 2 * L - 1;
    int s0 = 2 * L, s1 = 2 * L + 1;
    // skip taps h_1,h_3,h_5 at L=2,4,6 (h_7 folded in regressor). First tap stores.
    int smode = ((L - 1) & 1) ? ((L == 2) ? 1 : 2) : 0;
    agg128_kernel<<<(N + 3) / 4, 256, 0, stream>>>(
        YB, SA(sp), SC(sp), row_ptr, colb, eps, L, (uint_t*)X0u, SKIPu, smode, N);
    gemm_mfma<128, 0, 1><<<gg, 256, 0, stream>>>(
        nullptr, X0u, WBH(L), b1 + (size_t)(L - 1) * HID, nullptr, nullptr, X0u,
        SSTAT(s0), SA(s0), SC(s0), SCNT(s0),
        g_in + (size_t)L * HID, be_in + (size_t)L * HID, invN, N, gg);
    gemm_mfma<128, 1, 1><<<gg, 256, 0, stream>>>(
        nullptr, X0u, WBH(8 + L), b2 + (size_t)L * HID, SA(s0), SC(s0), YB,
        SSTAT(s1), SA(s1), SC(s1), SCNT(s1),
        g_out + (size_t)L * HID, be_out + (size_t)L * HID, invN, N, gg);
  }
  // Y7 in YB (fp16), slot 15 holds its outer-BN params

  // ---- regressor: op = 0.25*(SKIP fp16 + relu(a7*Y7+c7)); head output fp16 into X0u ----
  gemm_mfma<128, 2, 1><<<gg, 256, 0, stream>>>(
      (const float*)SKIPu, YB, WBH(16), br1, SA(15), SC(15), X0u,
      SSTAT(16), SA(16), SC(16), SCNT(16), gr, ber, invN, N, gg);
  finaldot_kernel<<<(N + 3) / 4, 256, 0, stream>>>(X0u, SA(16), SC(16), Wr2, br2, out, N);
#undef SLOT
#undef SSTAT
#undef SA
#undef SC
#undef SCNT
#undef WBH
}